// Round 8
// baseline (303.844 us; speedup 1.0000x reference)
//
#include <hip/hip_runtime.h>

#define HH 512
#define WW 512
#define PLANES 96          // 32 * 3
#define RSTRIP 64          // output rows per block; 74 iters
#define NPIX 25165824.0f   // 32*3*512*512

// Gaussian weights (sigma=1.5, K=11), symmetric; these exact constants gave absmax 0.0
#define G0 0.2660117f
#define G1 0.2130056f
#define G2 0.1093607f
#define G3 0.0360008f
#define G4 0.0075988f
#define G5 0.0010284f

#define C1F 1e-4f
#define C2F 9e-4f

typedef float v2f __attribute__((ext_vector_type(2)));
#define PKFMA(a, b, c) __builtin_elementwise_fma(a, b, c)

// 11-deep packed histories; now packed ACROSS THE 2 COLUMNS of a lane team.
// Even lane: SS=conv(u) [A], QQ=conv(u^2) [P]; odd lane: SS=conv(v) [B], QQ=conv(v^2) [Q].
#define DECL_HIST2(Z) v2f Z##0={0,0},Z##1={0,0},Z##2={0,0},Z##3={0,0},Z##4={0,0},\
                          Z##5={0,0},Z##6={0,0},Z##7={0,0},Z##8={0,0},Z##9={0,0},Z##10={0,0}
#define SHIFT_HIST(Z) do{Z##0=Z##1;Z##1=Z##2;Z##2=Z##3;Z##3=Z##4;Z##4=Z##5;\
                         Z##5=Z##6;Z##6=Z##7;Z##7=Z##8;Z##8=Z##9;Z##9=Z##10;}while(0)
// identical per-component op order as the scalar VCONV that measured absmax 0.0
#define VCONV2(Z) PKFMA(g5, Z##0+Z##10, PKFMA(g4, Z##1+Z##9, PKFMA(g3, Z##2+Z##8,\
                  PKFMA(g2, Z##3+Z##7, PKFMA(g1, Z##4+Z##6, g0*Z##5)))))

// horizontal conv, op order identical to the absmax-0.0 HPAIR sequence
#define HCONV(T0,T1,T2,T3,T4,T5,T6,T7,T8,T9,T10, NAB, NPQ) do { \
    NAB = g0 * (T5);            NPQ = g0 * ((T5) * (T5)); \
    NAB = PKFMA(g1, (T4)+(T6),  NAB); NPQ = PKFMA(g1, PKFMA((T4),(T4),(T6)*(T6)),   NPQ); \
    NAB = PKFMA(g2, (T3)+(T7),  NAB); NPQ = PKFMA(g2, PKFMA((T3),(T3),(T7)*(T7)),   NPQ); \
    NAB = PKFMA(g3, (T2)+(T8),  NAB); NPQ = PKFMA(g3, PKFMA((T2),(T2),(T8)*(T8)),   NPQ); \
    NAB = PKFMA(g4, (T1)+(T9),  NAB); NPQ = PKFMA(g4, PKFMA((T1),(T1),(T9)*(T9)),   NPQ); \
    NAB = PKFMA(g5, (T0)+(T10), NAB); NPQ = PKFMA(g5, PKFMA((T0),(T0),(T10)*(T10)), NPQ); \
} while (0)

// Round 14: R6 falsified work-reduction (-12% work -> -1% time): stall-bound
// at 26% occupancy (~2 waves/SIMD), which tracks live state (88-float
// histories). R5 proved budget-squeeze spills. Fix: HALVE THE STATE -- team
// of 2 lanes covers 2 columns; even lane owns u-streams (A,P) for both cols,
// odd lane owns v-streams (B,Q). History/lane: 44 floats. LDS = split u/v
// planes (v at +75 dwords = odd bank offset -> even/odd lanes on disjoint
// bank sets, all <=2-way = free). Each lane reads 12 consecutive dwords from
// its own plane; same HCONV/VCONV op order per component -> bit-exact.
// Epilogue exchanges the 2 cross-stream values via __shfl_xor(.,1).
// ~100 live regs -> waves_per_eu(4,8) without spill; target 4+ waves/SIMD.
__global__ __launch_bounds__(256) __attribute__((amdgpu_waves_per_eu(4, 8)))
void ssim_main(const float* __restrict__ img1,
               const float* __restrict__ img2,
               float* __restrict__ acc) {
    __shared__ float pl[4][150];   // per wave: u-plane dwords 0..73, v-plane 75..148
    const int tid  = threadIdx.x;
    const int lane = tid & 63;
    const int wv   = tid >> 6;
    const int base = blockIdx.x * 256 + wv * 64; // wave's 64 output columns
    const int r0   = blockIdx.y * RSTRIP;        // first output row of strip
    const int p    = blockIdx.z;                 // plane (b*3+ch)
    const size_t pb = (size_t)p * (HH * WW);

    // staging: lane stages col base-5+lane into slot lane; lanes<10 also stage
    // col base+59+lane into slot 64+lane (window needs cols base-5..base+68)
    const int cs = base - 5 + lane;
    const bool vmain = (unsigned)cs < (unsigned)WW;
    const bool hh    = lane < 10;
    const bool vhalo = hh && (unsigned)(cs + 64) < (unsigned)WW;

    // team decomposition
    const int tau   = lane >> 1;                 // team 0..31 -> cols base+2tau, +1
    const int alpha = lane & 1;                  // 0: u-streams, 1: v-streams
    const float* const wp = &pl[wv][alpha ? 75 : 0] + 2 * tau;  // taps wp[0..11]

    // row pointers at (t, cs); advanced by WW per iteration (deref is guarded)
    const float* rx = img1 + pb + (ptrdiff_t)(r0 - 5) * WW + cs;
    const float* ry = img2 + pb + (ptrdiff_t)(r0 - 5) * WW + cs;

    const v2f g0 = {G0, G0}, g1 = {G1, G1}, g2 = {G2, G2},
              g3 = {G3, G3}, g4 = {G4, G4}, g5 = {G5, G5};

    DECL_HIST2(SS); DECL_HIST2(QQ);              // this lane's 2 streams, 2 cols packed

    // prefetch first row (r0-5; guarded, may be <0 on first strip)
    float cx = 0.f, cy = 0.f, chx = 0.f, chy = 0.f;
    if ((unsigned)(r0 - 5) < (unsigned)HH) {
        if (vmain) { cx  = rx[0];  cy  = ry[0];  }
        if (vhalo) { chx = rx[64]; chy = ry[64]; }
    }

    float lsum = 0.f;
    const int tend = r0 + RSTRIP + 4;

#pragma unroll 6
    for (int t = r0 - 5; t <= tend; ++t, rx += WW, ry += WW) {
        SHIFT_HIST(SS); SHIFT_HIST(QQ);

        // issue next row's loads first; consumed next iteration (latency hidden)
        float nx = 0.f, ny = 0.f, nhx = 0.f, nhy = 0.f;
        const int tn = t + 1;
        if (tn <= tend && (unsigned)tn < (unsigned)HH) {
            if (vmain) { nx  = rx[WW];      ny  = ry[WW];      }
            if (vhalo) { nhx = rx[WW + 64]; nhy = ry[WW + 64]; }
        }

        v2f nS = {0.f, 0.f}, nQ = {0.f, 0.f};
        if ((unsigned)t < (unsigned)HH) {        // uniform across block
            float* const up = &pl[wv][0];
            up[lane]      = cx + cy;             // u-plane
            up[75 + lane] = cx - cy;             // v-plane (odd bank offset)
            if (hh) { up[64 + lane]  = chx + chy;
                      up[139 + lane] = chx - chy; }
            __asm__ volatile("" ::: "memory");
            __builtin_amdgcn_wave_barrier();

            // 12 consecutive taps from this lane's own plane
            const float u0 = wp[0], u1 = wp[1], u2 = wp[2],  u3 = wp[3];
            const float u4 = wp[4], u5 = wp[5], u6 = wp[6],  u7 = wp[7];
            const float u8 = wp[8], u9 = wp[9], uA = wp[10], uB = wp[11];
            // packed-across-columns taps: T_k = (tap k of col0, tap k of col1)
            const v2f T0 = {u0, u1}, T1 = {u1, u2}, T2 = {u2, u3}, T3 = {u3, u4};
            const v2f T4 = {u4, u5}, T5 = {u5, u6}, T6 = {u6, u7}, T7 = {u7, u8};
            const v2f T8 = {u8, u9}, T9 = {u9, uA}, TA = {uA, uB};
            HCONV(T0,T1,T2,T3,T4,T5,T6,T7,T8,T9,TA, nS, nQ);
            __asm__ volatile("" ::: "memory");
            __builtin_amdgcn_wave_barrier();     // next iter's writes stay below reads
        }
        cx = nx; cy = ny; chx = nhx; chy = nhy;
        SS10 = nS; QQ10 = nQ;

        const int s = t - 5 - r0;                // output row within strip
        if ((unsigned)s < (unsigned)RSTRIP) {    // uniform; first 10 iters warm up
            const v2f mu = VCONV2(SS);           // even: (mu_u c0, mu_u c1); odd: mu_v
            const v2f c2 = VCONV2(QQ);           // even: conv(u^2); odd: conv(v^2)
            // exchange: even needs odd's .x (col0); odd needs even's .y (col1)
            const float smu = alpha ? mu.x : mu.y;
            const float sc2 = alpha ? c2.x : c2.y;
            const float rmu = __shfl_xor(smu, 1, 64);
            const float rc2 = __shfl_xor(sc2, 1, 64);
            const float mu_u = alpha ? rmu  : mu.x;
            const float mu_v = alpha ? mu.y : rmu;
            const float cu2  = alpha ? rc2  : c2.x;
            const float cv2  = alpha ? c2.y : rc2;
            // epilogue, same op order as the absmax-0.0 kernel
            const float a = mu_u * mu_u;
            const float b = mu_v * mu_v;
            const float musq = 0.5f  * (a + b);      // mu1^2 + mu2^2
            const float mu12 = 0.25f * (a - b);      // mu1 * mu2
            const float csq  = 0.5f  * (cu2 + cv2);  // conv(x^2) + conv(y^2)
            const float cxy  = 0.25f * (cu2 - cv2);  // conv(x*y)
            const float ssum = csq - musq;           // sigma1^2 + sigma2^2
            const float s12  = cxy - mu12;           // sigma12
            const float num = fmaf(2.f, mu12, C1F) * fmaf(2.f, s12, C2F);
            const float den = (musq + C1F) * (ssum + C2F);
            lsum += num * __builtin_amdgcn_rcpf(den);
        }
    }

    // reduction: wave shfl -> LDS -> one atomic per block
#pragma unroll
    for (int off = 32; off > 0; off >>= 1)
        lsum += __shfl_down(lsum, off, 64);
    __shared__ float ws4[4];
    if (lane == 0) ws4[wv] = lsum;
    __syncthreads();
    if (threadIdx.x == 0)
        atomicAdd(acc, ws4[0] + ws4[1] + ws4[2] + ws4[3]);
}

__global__ void ssim_zero(float* acc) { acc[0] = 0.f; }

__global__ void ssim_finalize(const float* __restrict__ acc, float* __restrict__ out) {
    out[0] = 1.f - acc[0] * (1.f / NPIX);
}

extern "C" void kernel_launch(void* const* d_in, const int* in_sizes, int n_in,
                              void* d_out, int out_size, void* d_ws, size_t ws_size,
                              hipStream_t stream) {
    const float* img1 = (const float*)d_in[0];
    const float* img2 = (const float*)d_in[1];
    float* out = (float*)d_out;
    float* acc = (float*)d_ws;

    ssim_zero<<<1, 1, 0, stream>>>(acc);
    dim3 grid(WW / 256, HH / RSTRIP, PLANES);    // (2, 8, 96) = 1536 blocks
    ssim_main<<<grid, 256, 0, stream>>>(img1, img2, acc);
    ssim_finalize<<<1, 1, 0, stream>>>(acc, out);
}

// Round 9
// 251.056 us; speedup vs baseline: 1.2103x; 1.2103x over previous
//
#include <hip/hip_runtime.h>

#define HH 512
#define WW 512
#define PLANES 96          // 32 * 3
#define RSTRIP 64          // output rows per block; 74 iters
#define NPIX 25165824.0f   // 32*3*512*512

// Gaussian weights (sigma=1.5, K=11), symmetric; these exact constants gave absmax 0.0
#define G0 0.2660117f
#define G1 0.2130056f
#define G2 0.1093607f
#define G3 0.0360008f
#define G4 0.0075988f
#define G5 0.0010284f

#define C1F 1e-4f
#define C2F 9e-4f

typedef float v2f __attribute__((ext_vector_type(2)));
#define PKFMA(a, b, c) __builtin_elementwise_fma(a, b, c)

// packed 11-deep histories: AB = (conv(u), conv(v)), PQ = (conv(u^2), conv(v^2))
#define DECL_HIST2(Z) v2f Z##0={0,0},Z##1={0,0},Z##2={0,0},Z##3={0,0},Z##4={0,0},\
                          Z##5={0,0},Z##6={0,0},Z##7={0,0},Z##8={0,0},Z##9={0,0},Z##10={0,0}
#define SHIFT_HIST(Z) do{Z##0=Z##1;Z##1=Z##2;Z##2=Z##3;Z##3=Z##4;Z##4=Z##5;\
                         Z##5=Z##6;Z##6=Z##7;Z##7=Z##8;Z##8=Z##9;Z##9=Z##10;}while(0)
// identical per-component op order as the scalar VCONV that measured absmax 0.0
#define VCONV2(Z) PKFMA(g5, Z##0+Z##10, PKFMA(g4, Z##1+Z##9, PKFMA(g3, Z##2+Z##8,\
                  PKFMA(g2, Z##3+Z##7, PKFMA(g1, Z##4+Z##6, g0*Z##5)))))

// horizontal conv, op order identical to the absmax-0.0 HPAIR sequence
#define HCONV(T0,T1,T2,T3,T4,T5,T6,T7,T8,T9,T10, NAB, NPQ) do { \
    NAB = g0 * (T5);            NPQ = g0 * ((T5) * (T5)); \
    NAB = PKFMA(g1, (T4)+(T6),  NAB); NPQ = PKFMA(g1, PKFMA((T4),(T4),(T6)*(T6)),   NPQ); \
    NAB = PKFMA(g2, (T3)+(T7),  NAB); NPQ = PKFMA(g2, PKFMA((T3),(T3),(T7)*(T7)),   NPQ); \
    NAB = PKFMA(g3, (T2)+(T8),  NAB); NPQ = PKFMA(g3, PKFMA((T2),(T2),(T8)*(T8)),   NPQ); \
    NAB = PKFMA(g4, (T1)+(T9),  NAB); NPQ = PKFMA(g4, PKFMA((T1),(T1),(T9)*(T9)),   NPQ); \
    NAB = PKFMA(g5, (T0)+(T10), NAB); NPQ = PKFMA(g5, PKFMA((T0),(T0),(T10)*(T10)), NPQ); \
} while (0)

#define EPILOG(ZAB, ZPQ) do { \
    const v2f mu = VCONV2(ZAB); \
    const v2f c2 = VCONV2(ZPQ); \
    const float a = mu.x * mu.x; \
    const float b = mu.y * mu.y; \
    const float musq = 0.5f  * (a + b);       /* mu1^2 + mu2^2 */ \
    const float mu12 = 0.25f * (a - b);       /* mu1 * mu2     */ \
    const float csq  = 0.5f  * (c2.x + c2.y); /* conv(x^2)+conv(y^2) */ \
    const float cxy  = 0.25f * (c2.x - c2.y); /* conv(x*y)     */ \
    const float ssum = csq - musq; \
    const float s12  = cxy - mu12; \
    const float num = fmaf(2.f, mu12, C1F) * fmaf(2.f, s12, C2F); \
    const float den = (musq + C1F) * (ssum + C2F); \
    lsum += num * __builtin_amdgcn_rcpf(den); \
} while (0)

// Round 15: R7 (state split across lane pairs) regressed 126->171 despite
// occupancy 26->38% -- per-wave ILP per LDS round-trip halved; occupancy is
// not the binding axis. Back to R6 (125.9us). Residual theory: R6's 88-float
// histories exceed the (3,8) register cap -> allocator parks them in AGPRs
// (unified file); every shift drags v_accvgpr_read/write through the VALU,
// explaining measured VALU-busy (~93us) vs op-count floor (~49us).
// ONE-VARIABLE experiment: waves_per_eu (3,8) -> (2,8). 256-reg budget kills
// the AGPR shuttle; occupancy already ~2.1 waves/SIMD so residency unchanged.
// Everything else byte-identical to R6 -> bit-exact.
__global__ __launch_bounds__(256) __attribute__((amdgpu_waves_per_eu(2, 8)))
void ssim_main(const float* __restrict__ img1,
               const float* __restrict__ img2,
               float* __restrict__ acc) {
    __shared__ __align__(16) v2f luv[4][144];    // wave-private; slot s <-> col base+s-5
    const int tid  = threadIdx.x;
    const int lane = tid & 63;
    const int wv   = tid >> 6;
    const int base = wv * 128;                   // block spans the full 512-col row
    const int r0   = blockIdx.y * RSTRIP;        // first output row of strip
    const int p    = blockIdx.z;                 // plane (b*3+ch)
    const size_t pb = (size_t)p * (HH * WW);
    const int c0   = base + 2 * lane;            // first of this thread's 2 columns

    // halo: lanes 0..4 stage col base-5+lane (slot lane);
    //       lanes 5..11 stage col base+128+(lane-5) (slot 128+lane)
    const bool hl = (lane < 5);
    const bool hhalo = (lane < 12);
    int hcol = hl ? (base - 5 + lane) : (base + 123 + lane);
    const bool hv = hhalo && ((unsigned)hcol < (unsigned)WW);
    if (!hv) hcol = 0;                           // keep pointer sane; loads are guarded
    const int hslot = hl ? lane : (128 + lane);

    // row pointers at (t, col); advanced by WW per iteration (deref is guarded)
    const float* rx = img1 + pb + (ptrdiff_t)(r0 - 5) * WW + c0;
    const float* ry = img2 + pb + (ptrdiff_t)(r0 - 5) * WW + c0;
    const float* hx = img1 + pb + (ptrdiff_t)(r0 - 5) * WW + hcol;
    const float* hy = img2 + pb + (ptrdiff_t)(r0 - 5) * WW + hcol;

    const v2f g0 = {G0, G0}, g1 = {G1, G1}, g2 = {G2, G2},
              g3 = {G3, G3}, g4 = {G4, G4}, g5 = {G5, G5};

    DECL_HIST2(ABe); DECL_HIST2(PQe);            // even column (c0)
    DECL_HIST2(ABo); DECL_HIST2(PQo);            // odd column (c0+1)

    // prefetch first row (r0-5; guarded, may be <0 on first strip)
    v2f cxv = {0.f, 0.f}, cyv = {0.f, 0.f};
    float chx = 0.f, chy = 0.f;
    if ((unsigned)(r0 - 5) < (unsigned)HH) {
        __builtin_memcpy(&cxv, rx, 8);
        __builtin_memcpy(&cyv, ry, 8);
        if (hv) { chx = hx[0]; chy = hy[0]; }
    }

    v2f* const sb = &luv[wv][0];
    float lsum = 0.f;
    const int tend = r0 + RSTRIP + 4;

#pragma unroll 6
    for (int t = r0 - 5; t <= tend; ++t, rx += WW, ry += WW, hx += WW, hy += WW) {
        SHIFT_HIST(ABe); SHIFT_HIST(PQe); SHIFT_HIST(ABo); SHIFT_HIST(PQo);

        // issue next row's loads first; consumed next iteration (latency hidden)
        v2f nxv = {0.f, 0.f}, nyv = {0.f, 0.f};
        float nhx = 0.f, nhy = 0.f;
        const int tn = t + 1;
        if (tn <= tend && (unsigned)tn < (unsigned)HH) {
            __builtin_memcpy(&nxv, rx + WW, 8);
            __builtin_memcpy(&nyv, ry + WW, 8);
            if (hv) { nhx = hx[WW]; nhy = hy[WW]; }
        }

        v2f nABe = {0,0}, nPQe = {0,0}, nABo = {0,0}, nPQo = {0,0};
        if ((unsigned)t < (unsigned)HH) {        // uniform across block
            // stage (u,v) for own 2 cols (slots 2l+5, 2l+6) + halo (lanes<12)
            const v2f u2 = cxv + cyv;            // (u of col0, u of col1)
            const v2f w2 = cxv - cyv;            // (v of col0, v of col1)
            sb[2 * lane + 5] = v2f{u2.x, w2.x};
            sb[2 * lane + 6] = v2f{u2.y, w2.y};
            if (hhalo) sb[hslot] = v2f{chx + chy, chx - chy};
            __asm__ volatile("" ::: "memory");
            __builtin_amdgcn_wave_barrier();

            // 12-tap window, 16B-aligned -> 6x ds_read_b128
            const v2f* wp = sb + 2 * lane;       // slots 2l..2l+11 = cols c0-5..c0+6
            const v2f t0 = wp[0], t1 = wp[1], t2 = wp[2],  t3 = wp[3];
            const v2f t4 = wp[4], t5 = wp[5], t6 = wp[6],  t7 = wp[7];
            const v2f t8 = wp[8], t9 = wp[9], ta = wp[10], tb = wp[11];
            HCONV(t0,t1,t2,t3,t4,t5,t6,t7,t8,t9,ta, nABe, nPQe);   // col c0
            HCONV(t1,t2,t3,t4,t5,t6,t7,t8,t9,ta,tb, nABo, nPQo);   // col c0+1
            __asm__ volatile("" ::: "memory");
            __builtin_amdgcn_wave_barrier();     // next iter's writes stay below reads
        }
        cxv = nxv; cyv = nyv; chx = nhx; chy = nhy;
        ABe10 = nABe; PQe10 = nPQe; ABo10 = nABo; PQo10 = nPQo;

        const int s = t - 5 - r0;                // output row within strip
        if ((unsigned)s < (unsigned)RSTRIP) {    // uniform; first 10 iters warm up
            EPILOG(ABe, PQe);
            EPILOG(ABo, PQo);
        }
    }

    // reduction: wave shfl -> LDS -> one atomic per block
#pragma unroll
    for (int off = 32; off > 0; off >>= 1)
        lsum += __shfl_down(lsum, off, 64);
    __shared__ float ws4[4];
    if (lane == 0) ws4[wv] = lsum;
    __syncthreads();
    if (threadIdx.x == 0)
        atomicAdd(acc, ws4[0] + ws4[1] + ws4[2] + ws4[3]);
}

__global__ void ssim_zero(float* acc) { acc[0] = 0.f; }

__global__ void ssim_finalize(const float* __restrict__ acc, float* __restrict__ out) {
    out[0] = 1.f - acc[0] * (1.f / NPIX);
}

extern "C" void kernel_launch(void* const* d_in, const int* in_sizes, int n_in,
                              void* d_out, int out_size, void* d_ws, size_t ws_size,
                              hipStream_t stream) {
    const float* img1 = (const float*)d_in[0];
    const float* img2 = (const float*)d_in[1];
    float* out = (float*)d_out;
    float* acc = (float*)d_ws;

    ssim_zero<<<1, 1, 0, stream>>>(acc);
    dim3 grid(1, HH / RSTRIP, PLANES);           // (1, 8, 96) = 768 blocks
    ssim_main<<<grid, 256, 0, stream>>>(img1, img2, acc);
    ssim_finalize<<<1, 1, 0, stream>>>(acc, out);
}